// Round 1
// baseline (515.629 us; speedup 1.0000x reference)
//
#include <hip/hip_runtime.h>
#include <math.h>

#define N_NODES 10000
#define N_EDGES 640000
#define DIM     128
#define NCLS    10
#define NGRAPH  64

// ---------------- CSR construction ----------------

__global__ void deg_kernel(const int* __restrict__ dst, int* __restrict__ deg) {
    int e = blockIdx.x * blockDim.x + threadIdx.x;
    if (e < N_EDGES) atomicAdd(&deg[dst[e]], 1);
}

__global__ void dis_kernel(const int* __restrict__ deg, float* __restrict__ dis) {
    int v = blockIdx.x * blockDim.x + threadIdx.x;
    if (v < N_NODES) dis[v] = rsqrtf((float)deg[v] + 1.0f);  // +1 for self loop
}

// Single-block Hillis-Steele scan over N_NODES degrees -> exclusive rowptr.
__global__ void scan_kernel(const int* __restrict__ deg, int* __restrict__ rowptr) {
    __shared__ int sm[1024];
    __shared__ int carry;
    int t = threadIdx.x;
    if (t == 0) { carry = 0; rowptr[0] = 0; }
    __syncthreads();
    for (int base = 0; base < N_NODES; base += 1024) {
        int i = base + t;
        int v = (i < N_NODES) ? deg[i] : 0;
        sm[t] = v;
        __syncthreads();
        for (int off = 1; off < 1024; off <<= 1) {
            int add = (t >= off) ? sm[t - off] : 0;
            __syncthreads();
            sm[t] += add;
            __syncthreads();
        }
        if (i < N_NODES) rowptr[i + 1] = sm[t] + carry;
        __syncthreads();
        if (t == 0) carry += sm[1023];
        __syncthreads();
    }
}

__global__ void fill_kernel(const int* __restrict__ src, const int* __restrict__ dst,
                            const int* __restrict__ rowptr, int* __restrict__ cursor,
                            int* __restrict__ colidx) {
    int e = blockIdx.x * blockDim.x + threadIdx.x;
    if (e < N_EDGES) {
        int d = dst[e];
        int p = atomicAdd(&cursor[d], 1);
        colidx[rowptr[d] + p] = src[e];
    }
}

// ---------------- GCN layer ----------------

// g = (x @ W) * dis[row]   (fold the dis[src] factor into the GEMM epilogue)
// 256 threads = 2 rows x 128 cols. x-row read is wave-uniform (L1 broadcast),
// W read coalesced 512B/row-of-W.
__global__ void gemm_scale(const float* __restrict__ X, const float* __restrict__ W,
                           const float* __restrict__ dis, float* __restrict__ Gout) {
    int row = blockIdx.x * 2 + (threadIdx.x >> 7);
    int c   = threadIdx.x & 127;
    if (row >= N_NODES) return;
    const float* xr = X + row * DIM;
    float acc = 0.f;
    for (int k = 0; k < DIM; k += 4) {
        float4 a = *(const float4*)(xr + k);
        acc += a.x * W[(k + 0) * DIM + c];
        acc += a.y * W[(k + 1) * DIM + c];
        acc += a.z * W[(k + 2) * DIM + c];
        acc += a.w * W[(k + 3) * DIM + c];
    }
    Gout[row * DIM + c] = acc * dis[row];
}

// x_out[v] = relu( dis[v] * ( g[v] + sum_{u in in(v)} g[u] ) )
// one 128-thread block per node; 4-way unrolled gather for MLP.
__global__ void agg_kernel(const float* __restrict__ g, const int* __restrict__ rowptr,
                           const int* __restrict__ colidx, const float* __restrict__ dis,
                           float* __restrict__ xout) {
    int v = blockIdx.x;
    int t = threadIdx.x;
    int s = rowptr[v], e = rowptr[v + 1];
    float acc = g[v * DIM + t];
    float a0 = 0.f, a1 = 0.f, a2 = 0.f, a3 = 0.f;
    int k = s;
    for (; k + 4 <= e; k += 4) {
        int u0 = colidx[k + 0];
        int u1 = colidx[k + 1];
        int u2 = colidx[k + 2];
        int u3 = colidx[k + 3];
        a0 += g[u0 * DIM + t];
        a1 += g[u1 * DIM + t];
        a2 += g[u2 * DIM + t];
        a3 += g[u3 * DIM + t];
    }
    for (; k < e; k++) acc += g[colidx[k] * DIM + t];
    acc += (a0 + a1) + (a2 + a3);
    float r = dis[v] * acc;
    xout[v * DIM + t] = r > 0.f ? r : 0.f;
}

// ---------------- readout ----------------

// batch is sorted: block per graph, binary-search the segment, plain sum.
__global__ void pool_kernel(const float* __restrict__ x, const int* __restrict__ batch,
                            float* __restrict__ xr) {
    int gph = blockIdx.x;
    int t = threadIdx.x;
    int lo = 0, hi = N_NODES;
    while (lo < hi) { int m = (lo + hi) >> 1; if (batch[m] < gph) lo = m + 1; else hi = m; }
    int st = lo;
    hi = N_NODES;
    while (lo < hi) { int m = (lo + hi) >> 1; if (batch[m] < gph + 1) lo = m + 1; else hi = m; }
    int en = lo;
    float acc = 0.f;
    for (int n = st; n < en; n++) acc += x[n * DIM + t];
    xr[gph * DIM + t] = acc;
}

// logits = x @ fc_w + fc_b ; log_softmax. One wave (64 lanes) per node.
__global__ void head_kernel(const float* __restrict__ x, const float* __restrict__ fcw,
                            const float* __restrict__ fcb, float* __restrict__ out) {
    int node = blockIdx.x * 4 + (threadIdx.x >> 6);
    int lane = threadIdx.x & 63;
    if (node >= N_NODES) return;
    float xl = x[node * DIM + lane];
    float xh = x[node * DIM + 64 + lane];
    float lg[NCLS];
#pragma unroll
    for (int c = 0; c < NCLS; c++) {
        float p = xl * fcw[lane * NCLS + c] + xh * fcw[(lane + 64) * NCLS + c];
#pragma unroll
        for (int off = 32; off >= 1; off >>= 1) p += __shfl_xor(p, off, 64);
        lg[c] = p + fcb[c];
    }
    float m = lg[0];
#pragma unroll
    for (int c = 1; c < NCLS; c++) m = fmaxf(m, lg[c]);
    float s = 0.f;
#pragma unroll
    for (int c = 0; c < NCLS; c++) s += expf(lg[c] - m);
    float lse = m + logf(s);
    if (lane < NCLS) out[node * NCLS + lane] = lg[lane] - lse;
}

// ---------------- launch ----------------

extern "C" void kernel_launch(void* const* d_in, const int* in_sizes, int n_in,
                              void* d_out, int out_size, void* d_ws, size_t ws_size,
                              hipStream_t stream) {
    const float* x     = (const float*)d_in[0];
    const int*   ei    = (const int*)d_in[1];      // [2, E] int32
    const int*   src   = ei;
    const int*   dst   = ei + N_EDGES;
    const int*   batch = (const int*)d_in[2];
    const float* W[4]  = {(const float*)d_in[3], (const float*)d_in[4],
                          (const float*)d_in[5], (const float*)d_in[6]};
    const float* fcw   = (const float*)d_in[7];    // [128,10]
    const float* fcb   = (const float*)d_in[8];    // [10]

    float* out_ls = (float*)d_out;                 // [N,10]
    float* out_xr = out_ls + N_NODES * NCLS;       // [64,128]

    // workspace layout (all element offsets %4==0 -> 16B aligned)
    int*   deg    = (int*)d_ws;                    // N
    int*   cursor = deg + N_NODES;                 // N
    int*   rowptr = cursor + N_NODES;              // N+1 (padded to 10004)
    int*   colidx = rowptr + 10004;                // E
    float* dis    = (float*)(colidx + N_EDGES);    // N
    float* Gb     = dis + N_NODES;                 // N*D
    float* Xb     = Gb + N_NODES * DIM;            // N*D

    hipMemsetAsync(deg, 0, 2 * N_NODES * sizeof(int), stream);  // deg + cursor

    deg_kernel <<<(N_EDGES + 255) / 256, 256, 0, stream>>>(dst, deg);
    dis_kernel <<<(N_NODES + 255) / 256, 256, 0, stream>>>(deg, dis);
    scan_kernel<<<1, 1024, 0, stream>>>(deg, rowptr);
    fill_kernel<<<(N_EDGES + 255) / 256, 256, 0, stream>>>(src, dst, rowptr, cursor, colidx);

    const float* xin = x;
    for (int l = 0; l < 4; l++) {
        gemm_scale<<<N_NODES / 2, 256, 0, stream>>>(xin, W[l], dis, Gb);
        agg_kernel<<<N_NODES, DIM, 0, stream>>>(Gb, rowptr, colidx, dis, Xb);
        xin = Xb;
    }

    pool_kernel<<<NGRAPH, DIM, 0, stream>>>(Xb, batch, out_xr);
    head_kernel<<<(N_NODES + 3) / 4, 256, 0, stream>>>(Xb, fcw, fcb, out_ls);
}

// Round 2
// 381.101 us; speedup vs baseline: 1.3530x; 1.3530x over previous
//
#include <hip/hip_runtime.h>
#include <math.h>

#define N_NODES 10000
#define N_EDGES 640000
#define DIM     128
#define NCLS    10
#define NGRAPH  64

// ---------------- CSR construction ----------------

// rank[e] = arrival order of edge e at its dst -> fill needs no atomics.
__global__ void deg_rank_kernel(const int* __restrict__ dst, int* __restrict__ deg,
                                int* __restrict__ rank) {
    int e = blockIdx.x * blockDim.x + threadIdx.x;
    if (e < N_EDGES) rank[e] = atomicAdd(&deg[dst[e]], 1);
}

__global__ void dis_kernel(const int* __restrict__ deg, float* __restrict__ dis) {
    int v = blockIdx.x * blockDim.x + threadIdx.x;
    if (v < N_NODES) dis[v] = rsqrtf((float)deg[v] + 1.0f);  // +1 self loop
}

// Single-block shuffle-scan (2 barriers per 1024-chunk instead of 20).
__global__ void scan_kernel(const int* __restrict__ deg, int* __restrict__ rowptr) {
    __shared__ int wsum[16];
    __shared__ int s_carry;
    int t = threadIdx.x;
    int lane = t & 63, wv = t >> 6;
    if (t == 0) { s_carry = 0; rowptr[0] = 0; }
    __syncthreads();
    for (int base = 0; base < N_NODES; base += 1024) {
        int i = base + t;
        int v = (i < N_NODES) ? deg[i] : 0;
#pragma unroll
        for (int off = 1; off < 64; off <<= 1) {
            int u = __shfl_up(v, off, 64);
            if (lane >= off) v += u;
        }
        if (lane == 63) wsum[wv] = v;
        __syncthreads();
        if (wv == 0) {
            int s2 = (lane < 16) ? wsum[lane] : 0;
#pragma unroll
            for (int off = 1; off < 16; off <<= 1) {
                int u = __shfl_up(s2, off, 64);
                if (lane >= off) s2 += u;
            }
            if (lane < 16) wsum[lane] = s2;
        }
        __syncthreads();
        int pre = (wv > 0) ? wsum[wv - 1] : 0;
        int carry = s_carry;
        if (i < N_NODES) rowptr[i + 1] = v + pre + carry;
        __syncthreads();
        if (t == 1023) s_carry = carry + pre + v;
        __syncthreads();
    }
}

__global__ void fill_kernel(const int* __restrict__ src, const int* __restrict__ dst,
                            const int* __restrict__ rowptr, const int* __restrict__ rank,
                            int* __restrict__ colidx) {
    int e = blockIdx.x * blockDim.x + threadIdx.x;
    if (e < N_EDGES) colidx[rowptr[dst[e]] + rank[e]] = src[e];
}

// ---------------- GCN layer ----------------

// g = (x @ W) * dis[row]. 16 rows/block, 8 rows/thread: W element loaded once,
// reused across 8 rows in registers. W L2 traffic: 625 blocks x 64KB = 40MB/layer.
__global__ __launch_bounds__(256) void gemm_scale(const float* __restrict__ X,
                                                  const float* __restrict__ W,
                                                  const float* __restrict__ dis,
                                                  float* __restrict__ Gout) {
    int c    = threadIdx.x & 127;
    int rg   = threadIdx.x >> 7;          // 0/1
    int row0 = blockIdx.x * 16 + rg * 8;  // this thread's 8 rows
    const float* xb = X + row0 * DIM;
    float acc[8] = {0.f, 0.f, 0.f, 0.f, 0.f, 0.f, 0.f, 0.f};
    for (int k = 0; k < DIM; k += 4) {
        float w0 = W[(k + 0) * DIM + c];
        float w1 = W[(k + 1) * DIM + c];
        float w2 = W[(k + 2) * DIM + c];
        float w3 = W[(k + 3) * DIM + c];
#pragma unroll
        for (int r = 0; r < 8; r++) {
            float4 xv = *(const float4*)(xb + r * DIM + k);
            acc[r] += xv.x * w0 + xv.y * w1 + xv.z * w2 + xv.w * w3;
        }
    }
#pragma unroll
    for (int r = 0; r < 8; r++) {
        int row = row0 + r;
        Gout[row * DIM + c] = acc[r] * dis[row];
    }
}

// x_out[v] = relu( dis[v] * ( g[v] + sum_{u in in(v)} g[u] ) )
__global__ __launch_bounds__(128) void agg_kernel(const float* __restrict__ g,
                                                  const int* __restrict__ rowptr,
                                                  const int* __restrict__ colidx,
                                                  const float* __restrict__ dis,
                                                  float* __restrict__ xout) {
    int v = blockIdx.x;
    int t = threadIdx.x;
    int s = rowptr[v], e = rowptr[v + 1];
    float acc = g[v * DIM + t];
    float a0 = 0.f, a1 = 0.f, a2 = 0.f, a3 = 0.f;
    int k = s;
    for (; k + 8 <= e; k += 8) {
        int u0 = colidx[k + 0], u1 = colidx[k + 1];
        int u2 = colidx[k + 2], u3 = colidx[k + 3];
        int u4 = colidx[k + 4], u5 = colidx[k + 5];
        int u6 = colidx[k + 6], u7 = colidx[k + 7];
        a0 += g[u0 * DIM + t]; a1 += g[u1 * DIM + t];
        a2 += g[u2 * DIM + t]; a3 += g[u3 * DIM + t];
        a0 += g[u4 * DIM + t]; a1 += g[u5 * DIM + t];
        a2 += g[u6 * DIM + t]; a3 += g[u7 * DIM + t];
    }
    for (; k < e; k++) acc += g[colidx[k] * DIM + t];
    acc += (a0 + a1) + (a2 + a3);
    float r = dis[v] * acc;
    xout[v * DIM + t] = r > 0.f ? r : 0.f;
}

// ---------------- readout ----------------

// batch sorted: 16-node chunks, register-accumulate per segment, atomic flush
// on segment change (~1.5 flushes/block).
__global__ __launch_bounds__(128) void pool_kernel(const float* __restrict__ x,
                                                   const int* __restrict__ batch,
                                                   float* __restrict__ xr) {
    int start = blockIdx.x * 16;
    int end   = start + 16 < N_NODES ? start + 16 : N_NODES;
    int t = threadIdx.x;
    int b = batch[start];
    float acc = 0.f;
    for (int n = start; n < end; n++) {
        int bn = batch[n];
        if (bn != b) { atomicAdd(&xr[b * DIM + t], acc); acc = 0.f; b = bn; }
        acc += x[n * DIM + t];
    }
    atomicAdd(&xr[b * DIM + t], acc);
}

// logits = x @ fc_w + fc_b ; log_softmax. One wave per node.
__global__ void head_kernel(const float* __restrict__ x, const float* __restrict__ fcw,
                            const float* __restrict__ fcb, float* __restrict__ out) {
    int node = blockIdx.x * 4 + (threadIdx.x >> 6);
    int lane = threadIdx.x & 63;
    if (node >= N_NODES) return;
    float xl = x[node * DIM + lane];
    float xh = x[node * DIM + 64 + lane];
    float lg[NCLS];
#pragma unroll
    for (int c = 0; c < NCLS; c++) {
        float p = xl * fcw[lane * NCLS + c] + xh * fcw[(lane + 64) * NCLS + c];
#pragma unroll
        for (int off = 32; off >= 1; off >>= 1) p += __shfl_xor(p, off, 64);
        lg[c] = p + fcb[c];
    }
    float m = lg[0];
#pragma unroll
    for (int c = 1; c < NCLS; c++) m = fmaxf(m, lg[c]);
    float s = 0.f;
#pragma unroll
    for (int c = 0; c < NCLS; c++) s += expf(lg[c] - m);
    float lse = m + logf(s);
    if (lane < NCLS) out[node * NCLS + lane] = lg[lane] - lse;
}

// ---------------- launch ----------------

extern "C" void kernel_launch(void* const* d_in, const int* in_sizes, int n_in,
                              void* d_out, int out_size, void* d_ws, size_t ws_size,
                              hipStream_t stream) {
    const float* x     = (const float*)d_in[0];
    const int*   ei    = (const int*)d_in[1];      // [2, E] int32
    const int*   src   = ei;
    const int*   dst   = ei + N_EDGES;
    const int*   batch = (const int*)d_in[2];
    const float* W[4]  = {(const float*)d_in[3], (const float*)d_in[4],
                          (const float*)d_in[5], (const float*)d_in[6]};
    const float* fcw   = (const float*)d_in[7];    // [128,10]
    const float* fcb   = (const float*)d_in[8];    // [10]

    float* out_ls = (float*)d_out;                 // [N,10]
    float* out_xr = out_ls + N_NODES * NCLS;       // [64,128]

    // workspace layout
    int*   deg    = (int*)d_ws;                    // N
    int*   rowptr = deg + N_NODES;                 // N+1 (padded to 10004)
    int*   colidx = rowptr + 10004;                // E
    float* dis    = (float*)(colidx + N_EDGES);    // N
    float* Gb     = dis + N_NODES;                 // N*D
    float* Xb     = Gb + N_NODES * DIM;            // N*D
    int*   rank   = (int*)Gb;                      // E ints, dead before gemm writes Gb

    hipMemsetAsync(deg, 0, N_NODES * sizeof(int), stream);
    hipMemsetAsync(out_xr, 0, NGRAPH * DIM * sizeof(float), stream);

    deg_rank_kernel<<<(N_EDGES + 255) / 256, 256, 0, stream>>>(dst, deg, rank);
    dis_kernel     <<<(N_NODES + 255) / 256, 256, 0, stream>>>(deg, dis);
    scan_kernel    <<<1, 1024, 0, stream>>>(deg, rowptr);
    fill_kernel    <<<(N_EDGES + 255) / 256, 256, 0, stream>>>(src, dst, rowptr, rank, colidx);

    const float* xin = x;
    for (int l = 0; l < 4; l++) {
        gemm_scale<<<N_NODES / 16, 256, 0, stream>>>(xin, W[l], dis, Gb);
        agg_kernel<<<N_NODES, DIM, 0, stream>>>(Gb, rowptr, colidx, dis, Xb);
        xin = Xb;
    }

    pool_kernel<<<(N_NODES + 15) / 16, 128, 0, stream>>>(Xb, batch, out_xr);
    head_kernel<<<(N_NODES + 3) / 4, 256, 0, stream>>>(Xb, fcw, fcb, out_ls);
}

// Round 3
// 355.533 us; speedup vs baseline: 1.4503x; 1.0719x over previous
//
#include <hip/hip_runtime.h>
#include <math.h>

#define N_NODES 10000
#define N_EDGES 640000
#define DIM     128
#define NCLS    10
#define NGRAPH  64

typedef unsigned int uint32;
typedef unsigned short ushort16;

// ---------------- CSR construction ----------------

// rank[e] = arrival order of edge e at its dst -> fill needs no atomics.
__global__ void deg_rank_kernel(const int* __restrict__ dst, int* __restrict__ deg,
                                int* __restrict__ rank) {
    int e = blockIdx.x * blockDim.x + threadIdx.x;
    if (e < N_EDGES) rank[e] = atomicAdd(&deg[dst[e]], 1);
}

__global__ void dis_kernel(const int* __restrict__ deg, float* __restrict__ dis) {
    int v = blockIdx.x * blockDim.x + threadIdx.x;
    if (v < N_NODES) dis[v] = rsqrtf((float)deg[v] + 1.0f);  // +1 self loop
}

// Single-block shuffle-scan (2 barriers per 1024-chunk).
__global__ void scan_kernel(const int* __restrict__ deg, int* __restrict__ rowptr) {
    __shared__ int wsum[16];
    __shared__ int s_carry;
    int t = threadIdx.x;
    int lane = t & 63, wv = t >> 6;
    if (t == 0) { s_carry = 0; rowptr[0] = 0; }
    __syncthreads();
    for (int base = 0; base < N_NODES; base += 1024) {
        int i = base + t;
        int v = (i < N_NODES) ? deg[i] : 0;
#pragma unroll
        for (int off = 1; off < 64; off <<= 1) {
            int u = __shfl_up(v, off, 64);
            if (lane >= off) v += u;
        }
        if (lane == 63) wsum[wv] = v;
        __syncthreads();
        if (wv == 0) {
            int s2 = (lane < 16) ? wsum[lane] : 0;
#pragma unroll
            for (int off = 1; off < 16; off <<= 1) {
                int u = __shfl_up(s2, off, 64);
                if (lane >= off) s2 += u;
            }
            if (lane < 16) wsum[lane] = s2;
        }
        __syncthreads();
        int pre = (wv > 0) ? wsum[wv - 1] : 0;
        int carry = s_carry;
        if (i < N_NODES) rowptr[i + 1] = v + pre + carry;
        __syncthreads();
        if (t == 1023) s_carry = carry + pre + v;
        __syncthreads();
    }
}

__global__ void fill_kernel(const int* __restrict__ src, const int* __restrict__ dst,
                            const int* __restrict__ rowptr, const int* __restrict__ rank,
                            int* __restrict__ colidx) {
    int e = blockIdx.x * blockDim.x + threadIdx.x;
    if (e < N_EDGES) colidx[rowptr[dst[e]] + rank[e]] = src[e];
}

// ---------------- GCN layer ----------------

__device__ __forceinline__ ushort16 f32_to_bf16_rne(float f) {
    uint32 u = __float_as_uint(f);
    u = (u + 0x7fffu + ((u >> 16) & 1u)) >> 16;   // round-to-nearest-even
    return (ushort16)u;
}

// g = bf16( (x @ W) * dis[row] ). 16 rows/block, 8 rows/thread: W element
// loaded once, reused across 8 rows. Output bf16 halves agg gather traffic.
__global__ __launch_bounds__(256) void gemm_scale(const float* __restrict__ X,
                                                  const float* __restrict__ W,
                                                  const float* __restrict__ dis,
                                                  ushort16* __restrict__ Gh) {
    int c    = threadIdx.x & 127;
    int rg   = threadIdx.x >> 7;          // 0/1
    int row0 = blockIdx.x * 16 + rg * 8;  // this thread's 8 rows
    const float* xb = X + row0 * DIM;
    float acc[8] = {0.f, 0.f, 0.f, 0.f, 0.f, 0.f, 0.f, 0.f};
    for (int k = 0; k < DIM; k += 4) {
        float w0 = W[(k + 0) * DIM + c];
        float w1 = W[(k + 1) * DIM + c];
        float w2 = W[(k + 2) * DIM + c];
        float w3 = W[(k + 3) * DIM + c];
#pragma unroll
        for (int r = 0; r < 8; r++) {
            float4 xv = *(const float4*)(xb + r * DIM + k);
            acc[r] += xv.x * w0 + xv.y * w1 + xv.z * w2 + xv.w * w3;
        }
    }
#pragma unroll
    for (int r = 0; r < 8; r++) {
        int row = row0 + r;
        Gh[row * DIM + c] = f32_to_bf16_rne(acc[r] * dis[row]);
    }
}

// x_out[v] = relu( dis[v] * ( g[v] + sum_{u in in(v)} g[u] ) )
// 4 nodes/block, one wave (64 lanes) per node; each lane owns 2 features
// (one uint = 2 bf16): 256 B/edge coalesced wave gather, fp32 accumulation,
// 4-deep unroll for memory-level parallelism against L2/L3 latency.
__global__ __launch_bounds__(256) void agg_kernel(const ushort16* __restrict__ Gh,
                                                  const int* __restrict__ rowptr,
                                                  const int* __restrict__ colidx,
                                                  const float* __restrict__ dis,
                                                  float* __restrict__ xout) {
    int v    = blockIdx.x * 4 + (threadIdx.x >> 6);
    int lane = threadIdx.x & 63;
    const uint32* g32 = (const uint32*)Gh;   // rows of 64 uints (128 bf16)
    int s = rowptr[v], e = rowptr[v + 1];

    uint32 us = g32[v * 64 + lane];          // self term
    float a0 = __uint_as_float(us << 16);
    float a1 = __uint_as_float(us & 0xffff0000u);
    float b0 = 0.f, b1 = 0.f, c0 = 0.f, c1 = 0.f, d0 = 0.f, d1 = 0.f;

    int k = s;
    for (; k + 4 <= e; k += 4) {
        int u0 = colidx[k + 0], u1 = colidx[k + 1];
        int u2 = colidx[k + 2], u3 = colidx[k + 3];
        uint32 w0 = g32[u0 * 64 + lane];
        uint32 w1 = g32[u1 * 64 + lane];
        uint32 w2 = g32[u2 * 64 + lane];
        uint32 w3 = g32[u3 * 64 + lane];
        a0 += __uint_as_float(w0 << 16); a1 += __uint_as_float(w0 & 0xffff0000u);
        b0 += __uint_as_float(w1 << 16); b1 += __uint_as_float(w1 & 0xffff0000u);
        c0 += __uint_as_float(w2 << 16); c1 += __uint_as_float(w2 & 0xffff0000u);
        d0 += __uint_as_float(w3 << 16); d1 += __uint_as_float(w3 & 0xffff0000u);
    }
    for (; k < e; k++) {
        uint32 w = g32[colidx[k] * 64 + lane];
        a0 += __uint_as_float(w << 16);
        a1 += __uint_as_float(w & 0xffff0000u);
    }
    float dv = dis[v];
    float r0 = dv * ((a0 + b0) + (c0 + d0));
    float r1 = dv * ((a1 + b1) + (c1 + d1));
    float2 out;
    out.x = r0 > 0.f ? r0 : 0.f;
    out.y = r1 > 0.f ? r1 : 0.f;
    *(float2*)(xout + v * DIM + lane * 2) = out;
}

// ---------------- readout ----------------

// batch sorted: 16-node chunks, register-accumulate, atomic flush on change.
__global__ __launch_bounds__(128) void pool_kernel(const float* __restrict__ x,
                                                   const int* __restrict__ batch,
                                                   float* __restrict__ xr) {
    int start = blockIdx.x * 16;
    int end   = start + 16 < N_NODES ? start + 16 : N_NODES;
    int t = threadIdx.x;
    int b = batch[start];
    float acc = 0.f;
    for (int n = start; n < end; n++) {
        int bn = batch[n];
        if (bn != b) { atomicAdd(&xr[b * DIM + t], acc); acc = 0.f; b = bn; }
        acc += x[n * DIM + t];
    }
    atomicAdd(&xr[b * DIM + t], acc);
}

// logits = x @ fc_w + fc_b ; log_softmax. One wave per node.
__global__ void head_kernel(const float* __restrict__ x, const float* __restrict__ fcw,
                            const float* __restrict__ fcb, float* __restrict__ out) {
    int node = blockIdx.x * 4 + (threadIdx.x >> 6);
    int lane = threadIdx.x & 63;
    if (node >= N_NODES) return;
    float xl = x[node * DIM + lane];
    float xh = x[node * DIM + 64 + lane];
    float lg[NCLS];
#pragma unroll
    for (int c = 0; c < NCLS; c++) {
        float p = xl * fcw[lane * NCLS + c] + xh * fcw[(lane + 64) * NCLS + c];
#pragma unroll
        for (int off = 32; off >= 1; off >>= 1) p += __shfl_xor(p, off, 64);
        lg[c] = p + fcb[c];
    }
    float m = lg[0];
#pragma unroll
    for (int c = 1; c < NCLS; c++) m = fmaxf(m, lg[c]);
    float s = 0.f;
#pragma unroll
    for (int c = 0; c < NCLS; c++) s += expf(lg[c] - m);
    float lse = m + logf(s);
    if (lane < NCLS) out[node * NCLS + lane] = lg[lane] - lse;
}

// ---------------- launch ----------------

extern "C" void kernel_launch(void* const* d_in, const int* in_sizes, int n_in,
                              void* d_out, int out_size, void* d_ws, size_t ws_size,
                              hipStream_t stream) {
    const float* x     = (const float*)d_in[0];
    const int*   ei    = (const int*)d_in[1];      // [2, E] int32
    const int*   src   = ei;
    const int*   dst   = ei + N_EDGES;
    const int*   batch = (const int*)d_in[2];
    const float* W[4]  = {(const float*)d_in[3], (const float*)d_in[4],
                          (const float*)d_in[5], (const float*)d_in[6]};
    const float* fcw   = (const float*)d_in[7];    // [128,10]
    const float* fcb   = (const float*)d_in[8];    // [10]

    float* out_ls = (float*)d_out;                 // [N,10]
    float* out_xr = out_ls + N_NODES * NCLS;       // [64,128]

    // workspace layout (element offsets keep 16B alignment)
    int*      deg    = (int*)d_ws;                 // N
    int*      rowptr = deg + N_NODES;              // N+1 (padded to 10004)
    int*      colidx = rowptr + 10004;             // E
    int*      rank   = colidx + N_EDGES;           // E
    float*    dis    = (float*)(rank + N_EDGES);   // N
    ushort16* Gh     = (ushort16*)(dis + N_NODES); // N*D bf16
    float*    Xb     = (float*)(Gh + N_NODES * DIM); // N*D f32

    hipMemsetAsync(deg, 0, N_NODES * sizeof(int), stream);
    hipMemsetAsync(out_xr, 0, NGRAPH * DIM * sizeof(float), stream);

    deg_rank_kernel<<<(N_EDGES + 255) / 256, 256, 0, stream>>>(dst, deg, rank);
    dis_kernel     <<<(N_NODES + 255) / 256, 256, 0, stream>>>(deg, dis);
    scan_kernel    <<<1, 1024, 0, stream>>>(deg, rowptr);
    fill_kernel    <<<(N_EDGES + 255) / 256, 256, 0, stream>>>(src, dst, rowptr, rank, colidx);

    const float* xin = x;
    for (int l = 0; l < 4; l++) {
        gemm_scale<<<N_NODES / 16, 256, 0, stream>>>(xin, W[l], dis, Gh);
        agg_kernel<<<N_NODES / 4, 256, 0, stream>>>(Gh, rowptr, colidx, dis, Xb);
        xin = Xb;
    }

    pool_kernel<<<(N_NODES + 15) / 16, 128, 0, stream>>>(Xb, batch, out_xr);
    head_kernel<<<(N_NODES + 3) / 4, 256, 0, stream>>>(Xb, fcw, fcb, out_ls);
}

// Round 4
// 321.231 us; speedup vs baseline: 1.6052x; 1.1068x over previous
//
#include <hip/hip_runtime.h>
#include <math.h>

#define N_NODES 10000
#define N_EDGES 640000
#define DIM     128
#define NCLS    10
#define NGRAPH  64
#define CSTRIDE 256   // padded adjacency stride; in-degree ~Poisson(64), max ~105 << 256

typedef unsigned int uint32;
typedef unsigned short ushort16;

// ---------------- adjacency build (one kernel, no scan) ----------------

// col[d*CSTRIDE + rank] = src, rank from the same atomic that counts degree.
__global__ void build_kernel(const int* __restrict__ src, const int* __restrict__ dst,
                             int* __restrict__ deg, int* __restrict__ col) {
    int e = blockIdx.x * blockDim.x + threadIdx.x;
    if (e < N_EDGES) {
        int s = src[e];
        int d = dst[e];
        int r = atomicAdd(&deg[d], 1);
        col[(d << 8) + r] = s;
    }
}

// ---------------- GCN layer ----------------

__device__ __forceinline__ ushort16 f32_to_bf16_rne(float f) {
    uint32 u = __float_as_uint(f);
    u = (u + 0x7fffu + ((u >> 16) & 1u)) >> 16;   // round-to-nearest-even
    return (ushort16)u;
}

// g = bf16( (x @ W) * rsqrt(deg+1) ). 16 rows/block, 8 rows/thread: W element
// loaded once, reused across 8 rows. bf16 output halves agg gather traffic.
__global__ __launch_bounds__(256) void gemm_scale(const float* __restrict__ X,
                                                  const float* __restrict__ W,
                                                  const int* __restrict__ deg,
                                                  ushort16* __restrict__ Gh) {
    int c    = threadIdx.x & 127;
    int rg   = threadIdx.x >> 7;          // 0/1
    int row0 = blockIdx.x * 16 + rg * 8;  // this thread's 8 rows
    const float* xb = X + row0 * DIM;
    float acc[8] = {0.f, 0.f, 0.f, 0.f, 0.f, 0.f, 0.f, 0.f};
    for (int k = 0; k < DIM; k += 4) {
        float w0 = W[(k + 0) * DIM + c];
        float w1 = W[(k + 1) * DIM + c];
        float w2 = W[(k + 2) * DIM + c];
        float w3 = W[(k + 3) * DIM + c];
#pragma unroll
        for (int r = 0; r < 8; r++) {
            float4 xv = *(const float4*)(xb + r * DIM + k);
            acc[r] += xv.x * w0 + xv.y * w1 + xv.z * w2 + xv.w * w3;
        }
    }
#pragma unroll
    for (int r = 0; r < 8; r++) {
        int row = row0 + r;
        float di = rsqrtf((float)deg[row] + 1.0f);
        Gh[row * DIM + c] = f32_to_bf16_rne(acc[r] * di);
    }
}

// x_out[v] = relu( dis[v] * ( g[v] + sum_{u in in(v)} g[u] ) )
// 4 nodes/block, one wave per node; each lane owns 2 features (uint = 2 bf16):
// 256 B/edge coalesced wave gather, fp32 accumulation, 8-deep unroll for MLP.
__global__ __launch_bounds__(256) void agg_kernel(const ushort16* __restrict__ Gh,
                                                  const int* __restrict__ deg,
                                                  const int* __restrict__ col,
                                                  float* __restrict__ xout) {
    int v    = blockIdx.x * 4 + (threadIdx.x >> 6);
    int lane = threadIdx.x & 63;
    const uint32* g32 = (const uint32*)Gh;   // rows of 64 uints (128 bf16)
    const int* cv = col + (v << 8);
    int dv = deg[v];

    uint32 us = g32[(v << 6) + lane];        // self term
    float a0 = __uint_as_float(us << 16);
    float a1 = __uint_as_float(us & 0xffff0000u);
    float b0 = 0.f, b1 = 0.f, c0 = 0.f, c1 = 0.f;
    float d0 = 0.f, d1 = 0.f, e0 = 0.f, e1 = 0.f;
    float f0 = 0.f, f1 = 0.f, g0 = 0.f, g1 = 0.f;
    float h0 = 0.f, h1 = 0.f, i0 = 0.f, i1 = 0.f;

    int k = 0;
    for (; k + 8 <= dv; k += 8) {
        int4 q0 = *(const int4*)(cv + k);
        int4 q1 = *(const int4*)(cv + k + 4);
        uint32 w0 = g32[(q0.x << 6) + lane];
        uint32 w1 = g32[(q0.y << 6) + lane];
        uint32 w2 = g32[(q0.z << 6) + lane];
        uint32 w3 = g32[(q0.w << 6) + lane];
        uint32 w4 = g32[(q1.x << 6) + lane];
        uint32 w5 = g32[(q1.y << 6) + lane];
        uint32 w6 = g32[(q1.z << 6) + lane];
        uint32 w7 = g32[(q1.w << 6) + lane];
        a0 += __uint_as_float(w0 << 16); a1 += __uint_as_float(w0 & 0xffff0000u);
        b0 += __uint_as_float(w1 << 16); b1 += __uint_as_float(w1 & 0xffff0000u);
        c0 += __uint_as_float(w2 << 16); c1 += __uint_as_float(w2 & 0xffff0000u);
        d0 += __uint_as_float(w3 << 16); d1 += __uint_as_float(w3 & 0xffff0000u);
        e0 += __uint_as_float(w4 << 16); e1 += __uint_as_float(w4 & 0xffff0000u);
        f0 += __uint_as_float(w5 << 16); f1 += __uint_as_float(w5 & 0xffff0000u);
        g0 += __uint_as_float(w6 << 16); g1 += __uint_as_float(w6 & 0xffff0000u);
        h0 += __uint_as_float(w7 << 16); h1 += __uint_as_float(w7 & 0xffff0000u);
    }
    for (; k < dv; k++) {
        uint32 w = g32[(cv[k] << 6) + lane];
        i0 += __uint_as_float(w << 16);
        i1 += __uint_as_float(w & 0xffff0000u);
    }
    float di = rsqrtf((float)dv + 1.0f);
    float r0 = di * (((a0 + b0) + (c0 + d0)) + ((e0 + f0) + (g0 + h0)) + i0);
    float r1 = di * (((a1 + b1) + (c1 + d1)) + ((e1 + f1) + (g1 + h1)) + i1);
    float2 out;
    out.x = r0 > 0.f ? r0 : 0.f;
    out.y = r1 > 0.f ? r1 : 0.f;
    *(float2*)(xout + v * DIM + lane * 2) = out;
}

// ---------------- readout ----------------

// batch sorted: 16-node chunks, register-accumulate, atomic flush on change.
__global__ __launch_bounds__(128) void pool_kernel(const float* __restrict__ x,
                                                   const int* __restrict__ batch,
                                                   float* __restrict__ xr) {
    int start = blockIdx.x * 16;
    int end   = start + 16 < N_NODES ? start + 16 : N_NODES;
    int t = threadIdx.x;
    int b = batch[start];
    float acc = 0.f;
    for (int n = start; n < end; n++) {
        int bn = batch[n];
        if (bn != b) { atomicAdd(&xr[b * DIM + t], acc); acc = 0.f; b = bn; }
        acc += x[n * DIM + t];
    }
    atomicAdd(&xr[b * DIM + t], acc);
}

// logits = x @ fc_w + fc_b ; log_softmax. One wave per node.
__global__ void head_kernel(const float* __restrict__ x, const float* __restrict__ fcw,
                            const float* __restrict__ fcb, float* __restrict__ out) {
    int node = blockIdx.x * 4 + (threadIdx.x >> 6);
    int lane = threadIdx.x & 63;
    if (node >= N_NODES) return;
    float xl = x[node * DIM + lane];
    float xh = x[node * DIM + 64 + lane];
    float lg[NCLS];
#pragma unroll
    for (int c = 0; c < NCLS; c++) {
        float p = xl * fcw[lane * NCLS + c] + xh * fcw[(lane + 64) * NCLS + c];
#pragma unroll
        for (int off = 32; off >= 1; off >>= 1) p += __shfl_xor(p, off, 64);
        lg[c] = p + fcb[c];
    }
    float m = lg[0];
#pragma unroll
    for (int c = 1; c < NCLS; c++) m = fmaxf(m, lg[c]);
    float s = 0.f;
#pragma unroll
    for (int c = 0; c < NCLS; c++) s += expf(lg[c] - m);
    float lse = m + logf(s);
    if (lane < NCLS) out[node * NCLS + lane] = lg[lane] - lse;
}

// ---------------- launch ----------------

extern "C" void kernel_launch(void* const* d_in, const int* in_sizes, int n_in,
                              void* d_out, int out_size, void* d_ws, size_t ws_size,
                              hipStream_t stream) {
    const float* x     = (const float*)d_in[0];
    const int*   ei    = (const int*)d_in[1];      // [2, E] int32
    const int*   src   = ei;
    const int*   dst   = ei + N_EDGES;
    const int*   batch = (const int*)d_in[2];
    const float* W[4]  = {(const float*)d_in[3], (const float*)d_in[4],
                          (const float*)d_in[5], (const float*)d_in[6]};
    const float* fcw   = (const float*)d_in[7];    // [128,10]
    const float* fcb   = (const float*)d_in[8];    // [10]

    float* out_ls = (float*)d_out;                 // [N,10]
    float* out_xr = out_ls + N_NODES * NCLS;       // [64,128]

    // workspace layout (16B-aligned element offsets)
    int*      deg = (int*)d_ws;                    // N (pad to 10240)
    int*      col = deg + 10240;                   // N*CSTRIDE
    ushort16* Gh  = (ushort16*)(col + N_NODES * CSTRIDE); // N*D bf16
    float*    Xb  = (float*)(Gh + N_NODES * DIM);  // N*D f32

    hipMemsetAsync(deg, 0, N_NODES * sizeof(int), stream);
    hipMemsetAsync(out_xr, 0, NGRAPH * DIM * sizeof(float), stream);

    build_kernel<<<(N_EDGES + 255) / 256, 256, 0, stream>>>(src, dst, deg, col);

    const float* xin = x;
    for (int l = 0; l < 4; l++) {
        gemm_scale<<<N_NODES / 16, 256, 0, stream>>>(xin, W[l], deg, Gh);
        agg_kernel<<<N_NODES / 4, 256, 0, stream>>>(Gh, deg, col, Xb);
        xin = Xb;
    }

    pool_kernel<<<(N_NODES + 15) / 16, 128, 0, stream>>>(Xb, batch, out_xr);
    head_kernel<<<(N_NODES + 3) / 4, 256, 0, stream>>>(Xb, fcw, fcb, out_ls);
}

// Round 5
// 291.878 us; speedup vs baseline: 1.7666x; 1.1006x over previous
//
#include <hip/hip_runtime.h>
#include <math.h>

#define N_NODES 10000
#define N_EDGES 640000
#define DIM     128
#define NCLS    10
#define NGRAPH  64
#define CSTRIDE 256   // padded adjacency stride; in-degree ~Poisson(64), max ~110 << 256

typedef unsigned int uint32;
typedef unsigned short ushort16;

__device__ __forceinline__ ushort16 f32_to_bf16_rne(float f) {
    uint32 u = __float_as_uint(f);
    u = (u + 0x7fffu + ((u >> 16) & 1u)) >> 16;   // round-to-nearest-even
    return (ushort16)u;
}

// ---------------- fused adjacency build + layer-1 GEMM ----------------
// Blocks 0..624: g1 = bf16(x @ W1)  (UNSCALED - needs no deg, so it can run
// concurrently with build). Blocks 625..3124: scatter edges into padded
// ushort adjacency (2 B/entry halves the scattered-write drain vs int).
__global__ __launch_bounds__(256) void build_gemm1(const int* __restrict__ src,
                                                   const int* __restrict__ dst,
                                                   int* __restrict__ deg,
                                                   ushort16* __restrict__ col,
                                                   const float* __restrict__ X,
                                                   const float* __restrict__ W,
                                                   ushort16* __restrict__ Gh) {
    if (blockIdx.x < 625) {
        int c    = threadIdx.x & 127;
        int rg   = threadIdx.x >> 7;
        int row0 = blockIdx.x * 16 + rg * 8;
        const float* xb = X + row0 * DIM;
        float acc[8] = {0.f, 0.f, 0.f, 0.f, 0.f, 0.f, 0.f, 0.f};
        for (int k = 0; k < DIM; k += 4) {
            float w0 = W[(k + 0) * DIM + c];
            float w1 = W[(k + 1) * DIM + c];
            float w2 = W[(k + 2) * DIM + c];
            float w3 = W[(k + 3) * DIM + c];
#pragma unroll
            for (int r = 0; r < 8; r++) {
                float4 xv = *(const float4*)(xb + r * DIM + k);
                acc[r] += xv.x * w0 + xv.y * w1 + xv.z * w2 + xv.w * w3;
            }
        }
#pragma unroll
        for (int r = 0; r < 8; r++)
            Gh[(row0 + r) * DIM + c] = f32_to_bf16_rne(acc[r]);
    } else {
        int e = (blockIdx.x - 625) * 256 + threadIdx.x;
        if (e < N_EDGES) {
            int s = src[e];
            int d = dst[e];
            int r = atomicAdd(&deg[d], 1);
            if (r < CSTRIDE) col[(d << 8) + r] = (ushort16)s;
        }
    }
}

// ---------------- layer-1 aggregation (computes dis on the fly) ----------------
// out[v] = relu( sv * ( sv*g[v] + sum_u s_u*g[u] ) ), s = rsqrt(deg+1).
// Also writes dis[v]=sv for later layers. One wave per node, lane owns 2 feats.
__global__ __launch_bounds__(256) void agg1_kernel(const ushort16* __restrict__ Gh,
                                                   const int* __restrict__ deg,
                                                   const ushort16* __restrict__ col,
                                                   float* __restrict__ dis,
                                                   float* __restrict__ xout) {
    int v    = blockIdx.x * 4 + (threadIdx.x >> 6);
    int lane = threadIdx.x & 63;
    const uint32* g32 = (const uint32*)Gh;
    const ushort16* cv = col + (v << 8);
    int dv = deg[v];
    float sv = rsqrtf((float)dv + 1.0f);
    if (lane == 0) dis[v] = sv;

    uint32 us = g32[(v << 6) + lane];
    float a0 = sv * __uint_as_float(us << 16);
    float a1 = sv * __uint_as_float(us & 0xffff0000u);
    float b0 = 0.f, b1 = 0.f, c0 = 0.f, c1 = 0.f;
    float d0 = 0.f, d1 = 0.f, e0 = 0.f, e1 = 0.f;

    int k = 0;
    for (; k + 8 <= dv; k += 8) {
        uint4 q = *(const uint4*)(cv + k);
        int u0 = q.x & 0xffff, u1 = q.x >> 16;
        int u2 = q.y & 0xffff, u3 = q.y >> 16;
        int u4 = q.z & 0xffff, u5 = q.z >> 16;
        int u6 = q.w & 0xffff, u7 = q.w >> 16;
        uint32 w0 = g32[(u0 << 6) + lane];
        uint32 w1 = g32[(u1 << 6) + lane];
        uint32 w2 = g32[(u2 << 6) + lane];
        uint32 w3 = g32[(u3 << 6) + lane];
        uint32 w4 = g32[(u4 << 6) + lane];
        uint32 w5 = g32[(u5 << 6) + lane];
        uint32 w6 = g32[(u6 << 6) + lane];
        uint32 w7 = g32[(u7 << 6) + lane];
        float s0 = rsqrtf((float)deg[u0] + 1.0f);
        float s1 = rsqrtf((float)deg[u1] + 1.0f);
        float s2 = rsqrtf((float)deg[u2] + 1.0f);
        float s3 = rsqrtf((float)deg[u3] + 1.0f);
        float s4 = rsqrtf((float)deg[u4] + 1.0f);
        float s5 = rsqrtf((float)deg[u5] + 1.0f);
        float s6 = rsqrtf((float)deg[u6] + 1.0f);
        float s7 = rsqrtf((float)deg[u7] + 1.0f);
        a0 += s0 * __uint_as_float(w0 << 16); a1 += s0 * __uint_as_float(w0 & 0xffff0000u);
        b0 += s1 * __uint_as_float(w1 << 16); b1 += s1 * __uint_as_float(w1 & 0xffff0000u);
        c0 += s2 * __uint_as_float(w2 << 16); c1 += s2 * __uint_as_float(w2 & 0xffff0000u);
        d0 += s3 * __uint_as_float(w3 << 16); d1 += s3 * __uint_as_float(w3 & 0xffff0000u);
        a0 += s4 * __uint_as_float(w4 << 16); a1 += s4 * __uint_as_float(w4 & 0xffff0000u);
        b0 += s5 * __uint_as_float(w5 << 16); b1 += s5 * __uint_as_float(w5 & 0xffff0000u);
        c0 += s6 * __uint_as_float(w6 << 16); c1 += s6 * __uint_as_float(w6 & 0xffff0000u);
        d0 += s7 * __uint_as_float(w7 << 16); d1 += s7 * __uint_as_float(w7 & 0xffff0000u);
    }
    for (; k < dv; k++) {
        int u = cv[k];
        uint32 w = g32[(u << 6) + lane];
        float s = rsqrtf((float)deg[u] + 1.0f);
        e0 += s * __uint_as_float(w << 16);
        e1 += s * __uint_as_float(w & 0xffff0000u);
    }
    float r0 = sv * (((a0 + b0) + (c0 + d0)) + e0);
    float r1 = sv * (((a1 + b1) + (c1 + d1)) + e1);
    float2 out;
    out.x = r0 > 0.f ? r0 : 0.f;
    out.y = r1 > 0.f ? r1 : 0.f;
    *(float2*)(xout + v * DIM + lane * 2) = out;
}

// ---------------- layers 2-4 ----------------

// g = bf16( (x @ W) * dis[row] )
__global__ __launch_bounds__(256) void gemm_scale(const float* __restrict__ X,
                                                  const float* __restrict__ W,
                                                  const float* __restrict__ dis,
                                                  ushort16* __restrict__ Gh) {
    int c    = threadIdx.x & 127;
    int rg   = threadIdx.x >> 7;
    int row0 = blockIdx.x * 16 + rg * 8;
    const float* xb = X + row0 * DIM;
    float acc[8] = {0.f, 0.f, 0.f, 0.f, 0.f, 0.f, 0.f, 0.f};
    for (int k = 0; k < DIM; k += 4) {
        float w0 = W[(k + 0) * DIM + c];
        float w1 = W[(k + 1) * DIM + c];
        float w2 = W[(k + 2) * DIM + c];
        float w3 = W[(k + 3) * DIM + c];
#pragma unroll
        for (int r = 0; r < 8; r++) {
            float4 xv = *(const float4*)(xb + r * DIM + k);
            acc[r] += xv.x * w0 + xv.y * w1 + xv.z * w2 + xv.w * w3;
        }
    }
#pragma unroll
    for (int r = 0; r < 8; r++) {
        int row = row0 + r;
        Gh[row * DIM + c] = f32_to_bf16_rne(acc[r] * dis[row]);
    }
}

// x_out[v] = relu( dis[v] * ( g[v] + sum_u g[u] ) )   (g already dis-scaled)
__global__ __launch_bounds__(256) void agg_kernel(const ushort16* __restrict__ Gh,
                                                  const int* __restrict__ deg,
                                                  const ushort16* __restrict__ col,
                                                  const float* __restrict__ dis,
                                                  float* __restrict__ xout) {
    int v    = blockIdx.x * 4 + (threadIdx.x >> 6);
    int lane = threadIdx.x & 63;
    const uint32* g32 = (const uint32*)Gh;
    const ushort16* cv = col + (v << 8);
    int dv = deg[v];

    uint32 us = g32[(v << 6) + lane];
    float a0 = __uint_as_float(us << 16);
    float a1 = __uint_as_float(us & 0xffff0000u);
    float b0 = 0.f, b1 = 0.f, c0 = 0.f, c1 = 0.f;
    float d0 = 0.f, d1 = 0.f, e0 = 0.f, e1 = 0.f;
    float f0 = 0.f, f1 = 0.f, g0 = 0.f, g1 = 0.f;
    float h0 = 0.f, h1 = 0.f, i0 = 0.f, i1 = 0.f;

    int k = 0;
    for (; k + 8 <= dv; k += 8) {
        uint4 q = *(const uint4*)(cv + k);
        int u0 = q.x & 0xffff, u1 = q.x >> 16;
        int u2 = q.y & 0xffff, u3 = q.y >> 16;
        int u4 = q.z & 0xffff, u5 = q.z >> 16;
        int u6 = q.w & 0xffff, u7 = q.w >> 16;
        uint32 w0 = g32[(u0 << 6) + lane];
        uint32 w1 = g32[(u1 << 6) + lane];
        uint32 w2 = g32[(u2 << 6) + lane];
        uint32 w3 = g32[(u3 << 6) + lane];
        uint32 w4 = g32[(u4 << 6) + lane];
        uint32 w5 = g32[(u5 << 6) + lane];
        uint32 w6 = g32[(u6 << 6) + lane];
        uint32 w7 = g32[(u7 << 6) + lane];
        a0 += __uint_as_float(w0 << 16); a1 += __uint_as_float(w0 & 0xffff0000u);
        b0 += __uint_as_float(w1 << 16); b1 += __uint_as_float(w1 & 0xffff0000u);
        c0 += __uint_as_float(w2 << 16); c1 += __uint_as_float(w2 & 0xffff0000u);
        d0 += __uint_as_float(w3 << 16); d1 += __uint_as_float(w3 & 0xffff0000u);
        e0 += __uint_as_float(w4 << 16); e1 += __uint_as_float(w4 & 0xffff0000u);
        f0 += __uint_as_float(w5 << 16); f1 += __uint_as_float(w5 & 0xffff0000u);
        g0 += __uint_as_float(w6 << 16); g1 += __uint_as_float(w6 & 0xffff0000u);
        h0 += __uint_as_float(w7 << 16); h1 += __uint_as_float(w7 & 0xffff0000u);
    }
    for (; k < dv; k++) {
        uint32 w = g32[(cv[k] << 6) + lane];
        i0 += __uint_as_float(w << 16);
        i1 += __uint_as_float(w & 0xffff0000u);
    }
    float di = dis[v];
    float r0 = di * ((((a0 + b0) + (c0 + d0)) + ((e0 + f0) + (g0 + h0))) + i0);
    float r1 = di * ((((a1 + b1) + (c1 + d1)) + ((e1 + f1) + (g1 + h1))) + i1);
    float2 out;
    out.x = r0 > 0.f ? r0 : 0.f;
    out.y = r1 > 0.f ? r1 : 0.f;
    *(float2*)(xout + v * DIM + lane * 2) = out;
}

// ---------------- fused readout: pool (blocks 0-624) + head (625-3124) ----------------

__global__ __launch_bounds__(256) void pool_head(const float* __restrict__ x,
                                                 const int* __restrict__ batch,
                                                 const float* __restrict__ fcw,
                                                 const float* __restrict__ fcb,
                                                 float* __restrict__ xr,
                                                 float* __restrict__ out) {
    if (blockIdx.x < 625) {
        if (threadIdx.x >= 128) return;
        int start = blockIdx.x * 16;
        int t = threadIdx.x;
        int b = batch[start];
        float acc = 0.f;
        for (int n = start; n < start + 16; n++) {
            int bn = batch[n];
            if (bn != b) { atomicAdd(&xr[b * DIM + t], acc); acc = 0.f; b = bn; }
            acc += x[n * DIM + t];
        }
        atomicAdd(&xr[b * DIM + t], acc);
    } else {
        int node = (blockIdx.x - 625) * 4 + (threadIdx.x >> 6);
        int lane = threadIdx.x & 63;
        if (node >= N_NODES) return;
        float xl = x[node * DIM + lane];
        float xh = x[node * DIM + 64 + lane];
        float lg[NCLS];
#pragma unroll
        for (int c = 0; c < NCLS; c++) {
            float p = xl * fcw[lane * NCLS + c] + xh * fcw[(lane + 64) * NCLS + c];
#pragma unroll
            for (int off = 32; off >= 1; off >>= 1) p += __shfl_xor(p, off, 64);
            lg[c] = p + fcb[c];
        }
        float m = lg[0];
#pragma unroll
        for (int c = 1; c < NCLS; c++) m = fmaxf(m, lg[c]);
        float s = 0.f;
#pragma unroll
        for (int c = 0; c < NCLS; c++) s += expf(lg[c] - m);
        float lse = m + logf(s);
        if (lane < NCLS) out[node * NCLS + lane] = lg[lane] - lse;
    }
}

// ---------------- launch ----------------

extern "C" void kernel_launch(void* const* d_in, const int* in_sizes, int n_in,
                              void* d_out, int out_size, void* d_ws, size_t ws_size,
                              hipStream_t stream) {
    const float* x     = (const float*)d_in[0];
    const int*   ei    = (const int*)d_in[1];      // [2, E] int32
    const int*   src   = ei;
    const int*   dst   = ei + N_EDGES;
    const int*   batch = (const int*)d_in[2];
    const float* W[4]  = {(const float*)d_in[3], (const float*)d_in[4],
                          (const float*)d_in[5], (const float*)d_in[6]};
    const float* fcw   = (const float*)d_in[7];
    const float* fcb   = (const float*)d_in[8];

    float* out_ls = (float*)d_out;                 // [N,10]
    float* out_xr = out_ls + N_NODES * NCLS;       // [64,128]

    // workspace layout (16B-aligned)
    int*      deg = (int*)d_ws;                        // 10240 ints
    ushort16* col = (ushort16*)(deg + 10240);          // N*CSTRIDE ushorts (5.12MB)
    float*    dis = (float*)(col + N_NODES * CSTRIDE); // 10240 floats
    ushort16* Gh  = (ushort16*)(dis + 10240);          // N*D bf16
    float*    Xb  = (float*)(Gh + N_NODES * DIM);      // N*D f32

    hipMemsetAsync(deg, 0, 10240 * sizeof(int), stream);
    hipMemsetAsync(out_xr, 0, NGRAPH * DIM * sizeof(float), stream);

    build_gemm1<<<3125, 256, 0, stream>>>(src, dst, deg, col, x, W[0], Gh);
    agg1_kernel<<<N_NODES / 4, 256, 0, stream>>>(Gh, deg, col, dis, Xb);

    for (int l = 1; l < 4; l++) {
        gemm_scale<<<N_NODES / 16, 256, 0, stream>>>(Xb, W[l], dis, Gh);
        agg_kernel<<<N_NODES / 4, 256, 0, stream>>>(Gh, deg, col, dis, Xb);
    }

    pool_head<<<3125, 256, 0, stream>>>(Xb, batch, fcw, fcb, out_xr, out_ls);
}